// Round 8
// baseline (550.036 us; speedup 1.0000x reference)
//
#include <hip/hip_runtime.h>
#include <hip/hip_bf16.h>

#define HWDIM 1024             // 32*32
#define DDIM 256
#define KCODES 1024
#define NROWS 32768            // 32 * 1024
#define BSTRIDE (DDIM * HWDIM) // per-batch stride = 262144
#define GUARD 1.5e-4f          // certified gap (covers 2x dist roundings @256 + split err)

typedef __attribute__((ext_vector_type(8))) short short8;
typedef __attribute__((ext_vector_type(4))) float f32x4;
typedef __attribute__((ext_vector_type(2))) float f32x2;
typedef unsigned long long ull;

// ---- ws byte layout ----
// wT    @0        (1048576)  fp32 codebook transposed [256][1024] (fallback)
// ss    @1048576  (4096)     ||e_k||^2 numpy-pairwise
// gbest @1052672  (262144)   packed (ordered_dist<<32|k) per row
// hist  @1314816  (4096)
// flags @1318912  (131072)   int per row: 1 = needs exact fallback
// loss  @1449984  (8)        double
// ---- scratch in d_out encodings region (overwritten later by k_enc) ----
// ob = (char*)d_out + 33554448: wh8 @0 (524288), wl8 @524288 (524288)

__device__ __forceinline__ unsigned short f2bf(float v) {
  __hip_bfloat16 b = __float2bfloat16(v);
  return *reinterpret_cast<unsigned short*>(&b);
}
__device__ __forceinline__ float bf2f(unsigned short u) {
  __hip_bfloat16 b;
  *reinterpret_cast<unsigned short*>(&b) = u;
  return __bfloat162float(b);
}
__device__ __forceinline__ ull pk(float d, int k) {
  unsigned ub = __float_as_uint(d);
  ub = (ub & 0x80000000u) ? ~ub : (ub | 0x80000000u);  // monotone total order
  return ((ull)ub << 32) | (unsigned)k;
}
__device__ __forceinline__ float keyq(ull key) {
  unsigned ub = (unsigned)(key >> 32);
  unsigned orig = (ub & 0x80000000u) ? (ub & 0x7FFFFFFFu) : ~ub;
  return __uint_as_float(orig);
}

// numpy-exact pairwise sum of squares over 128 elements
__device__ __forceinline__ float pair128_sq(const float* p, int stride) {
  float a[8];
#pragma unroll
  for (int j = 0; j < 8; ++j) { float v = p[j * stride]; a[j] = __fmul_rn(v, v); }
  for (int i = 8; i < 128; i += 8) {
#pragma unroll
    for (int j = 0; j < 8; ++j) {
      float v = p[(i + j) * stride];
      a[j] = __fadd_rn(a[j], __fmul_rn(v, v));
    }
  }
  float s01 = __fadd_rn(a[0], a[1]), s23 = __fadd_rn(a[2], a[3]);
  float s45 = __fadd_rn(a[4], a[5]), s67 = __fadd_rn(a[6], a[7]);
  return __fadd_rn(__fadd_rn(s01, s23), __fadd_rn(s45, s67));
}

// prep: w bf16 hi/lo split [oct][k][8], wT transpose, ss, inits. grid 128.
__global__ __launch_bounds__(256) void k_prep(
    const float* __restrict__ w, float* __restrict__ wT, float* __restrict__ ss,
    int* __restrict__ hist, double* __restrict__ loss,
    unsigned short* __restrict__ wh8, unsigned short* __restrict__ wl8) {
  __shared__ float tile[64][65];
  const int t = threadIdx.x;
  int g = blockIdx.x * 256 + t;   // 32768 = 1024 k x 32 octets
  {
    int k = g >> 5, oct = g & 31;
    const float* p = w + k * DDIM + oct * 8;
    short8 hv, lv;
#pragma unroll
    for (int j = 0; j < 8; ++j) {
      float v = p[j];
      unsigned short h = f2bf(v);
      unsigned short l = f2bf(__fsub_rn(v, bf2f(h)));
      hv[j] = (short)h; lv[j] = (short)l;
    }
    *(short8*)&wh8[oct * 8192 + k * 8] = hv;
    *(short8*)&wl8[oct * 8192 + k * 8] = lv;
  }
  if (g < KCODES) {
    hist[g] = 0;
    const float* p = w + g * DDIM;
    ss[g] = __fadd_rn(pair128_sq(p, 1), pair128_sq(p + 128, 1));
  }
  if (g == 0) *loss = 0.0;
  // transpose (blocks 0..63): w[k][d] -> wT[d][k], 64x64 tiles
  if (blockIdx.x < 64) {
    const int k0 = (blockIdx.x & 15) * 64, d0 = (blockIdx.x >> 4) * 64;
    const int c = t & 63, r = t >> 6;
#pragma unroll
    for (int m = 0; m < 16; ++m)
      tile[r + m * 4][c] = w[(k0 + r + m * 4) * DDIM + d0 + c];
    __syncthreads();
#pragma unroll
    for (int m = 0; m < 16; ++m)
      wT[(size_t)(d0 + r + m * 4) * KCODES + k0 + c] = tile[c][r + m * 4];
  }
}

// single-pass MFMA argmin: block = 64 rows x ALL 1024 codes. grid 512.
// Each wave covers all 64 rows x a disjoint 32-code column per 128-code kb
// -> B (codebook split) read exactly ONCE per block from L2 (halved vs R6).
// A split to bf16 h/l in LDS [oct][row][8]; no barriers in K-loop.
__global__ __launch_bounds__(256, 2) void k_argmfma(
    const float* __restrict__ in,
    const unsigned short* __restrict__ wh8, const unsigned short* __restrict__ wl8,
    const float* __restrict__ ss, ull* __restrict__ gbest, int* __restrict__ flags) {
  __shared__ __align__(16) unsigned short Ah[32 * 64 * 8];  // 32 KB
  __shared__ __align__(16) unsigned short Al[32 * 64 * 8];  // 32 KB
  __shared__ ull best1[64], best2[64];

  const int t = threadIdx.x;
  const int n0 = blockIdx.x * 64;       // 64 | 1024 -> single batch per block
  const int b = n0 >> 10, hw0 = n0 & 1023;

  // ---- in-kernel split of x rows into LDS (bit-identical formulas to R6) ----
  {
    const int hw = t & 63, dg = t >> 6;
    const float* xp = in + b * BSTRIDE + hw0 + hw;
#pragma unroll
    for (int dd = 0; dd < 64; dd += 2) {
      int d = dg * 64 + dd;
      float f0 = xp[d * HWDIM], f1 = xp[(d + 1) * HWDIM];
      unsigned short h0 = f2bf(f0);
      unsigned short l0 = f2bf(__fsub_rn(f0, bf2f(h0)));
      unsigned short h1 = f2bf(f1);
      unsigned short l1 = f2bf(__fsub_rn(f1, bf2f(h1)));
      int base = ((d >> 3) * 64 + hw) * 8 + (d & 7);   // d even -> u32 pack ok
      *(unsigned*)&Ah[base] = (unsigned)h0 | ((unsigned)h1 << 16);
      *(unsigned*)&Al[base] = (unsigned)l0 | ((unsigned)l1 << 16);
    }
  }
  if (t < 64) { best1[t] = ~0ull; best2[t] = ~0ull; }
  __syncthreads();

  const int wv = t >> 6, ln = t & 63;
  const int cw = wv * 32;               // wave's 32-code column within each kb
  const int l15 = ln & 15, quad = ln >> 4;

  ull rb1[16], rb2[16];                 // running best/2nd per (rt,reg) row
#pragma unroll
  for (int i = 0; i < 16; ++i) { rb1[i] = ~0ull; rb2[i] = ~0ull; }

  for (int kb = 0; kb < 8; ++kb) {
    const int cb = kb * 128 + cw;
    f32x4 acc[4][2];
#pragma unroll
    for (int rt = 0; rt < 4; ++rt)
#pragma unroll
      for (int ct = 0; ct < 2; ++ct) acc[rt][ct] = (f32x4){0.f, 0.f, 0.f, 0.f};

#pragma unroll
    for (int ki = 0; ki < 8; ++ki) {
      const int obase = ki * 4 + quad;
      short8 ah[4], al[4], bh[2], bl[2];
#pragma unroll
      for (int ct = 0; ct < 2; ++ct) {
        int off = obase * 8192 + (cb + ct * 16 + l15) * 8;
        bh[ct] = *(const short8*)&wh8[off];
        bl[ct] = *(const short8*)&wl8[off];
      }
#pragma unroll
      for (int rt = 0; rt < 4; ++rt) {
        int row = rt * 16 + l15;
        ah[rt] = *(const short8*)&Ah[(obase * 64 + row) * 8];
        al[rt] = *(const short8*)&Al[(obase * 64 + row) * 8];
      }
#pragma unroll
      for (int rt = 0; rt < 4; ++rt)
#pragma unroll
        for (int ct = 0; ct < 2; ++ct) {
          acc[rt][ct] = __builtin_amdgcn_mfma_f32_16x16x32_bf16(ah[rt], bh[ct], acc[rt][ct], 0, 0, 0);
          acc[rt][ct] = __builtin_amdgcn_mfma_f32_16x16x32_bf16(ah[rt], bl[ct], acc[rt][ct], 0, 0, 0);
          acc[rt][ct] = __builtin_amdgcn_mfma_f32_16x16x32_bf16(al[rt], bh[ct], acc[rt][ct], 0, 0, 0);
        }
    }

    // fold this kb's 32 codes into running per-row top-2 (lane-local)
    float sv[2];
#pragma unroll
    for (int ct = 0; ct < 2; ++ct) sv[ct] = ss[cb + ct * 16 + l15];
#pragma unroll
    for (int rt = 0; rt < 4; ++rt)
#pragma unroll
      for (int reg = 0; reg < 4; ++reg) {
        int idx = rt * 4 + reg;
        ull b1 = rb1[idx], b2 = rb2[idx];
#pragma unroll
        for (int ct = 0; ct < 2; ++ct) {
          float q = fmaf(-2.f, acc[rt][ct][reg], sv[ct]);
          ull key = pk(q, cb + ct * 16 + l15);
          if (key < b1) { b2 = b1; b1 = key; } else if (key < b2) { b2 = key; }
        }
        rb1[idx] = b1; rb2[idx] = b2;
      }
  }

  // two-pass block merge: global best, then global 2nd
#pragma unroll
  for (int rt = 0; rt < 4; ++rt)
#pragma unroll
    for (int reg = 0; reg < 4; ++reg)
      atomicMin(&best1[rt * 16 + quad * 4 + reg], rb1[rt * 4 + reg]);
  __syncthreads();
#pragma unroll
  for (int rt = 0; rt < 4; ++rt)
#pragma unroll
    for (int reg = 0; reg < 4; ++reg) {
      int row = rt * 16 + quad * 4 + reg;
      int idx = rt * 4 + reg;
      ull sub = (rb1[idx] == best1[row]) ? rb2[idx] : rb1[idx];
      atomicMin(&best2[row], sub);
    }
  __syncthreads();
  if (t < 64) {
    ull k1 = best1[t];
    gbest[n0 + t] = k1;
    flags[n0 + t] = (keyq(best2[t]) - keyq(k1) > GUARD) ? 0 : 1;
  }
}

// exact fallback for flagged rows + hist + quantized_st/loss. grid 512.
__global__ __launch_bounds__(256) void k_quant(
    const float* __restrict__ in, const float* __restrict__ w,
    const float* __restrict__ wT, const float* __restrict__ ss,
    ull* __restrict__ gbest, const int* __restrict__ flags,
    int* __restrict__ hist, float* __restrict__ outq, double* __restrict__ loss) {
  __shared__ unsigned kk[64];
  __shared__ int flist[64];
  __shared__ int nflag;
  __shared__ float xrow[256];
  __shared__ float rsh;
  __shared__ ull bmin;
  __shared__ float wrow[64][65];
  __shared__ double red[256];

  const int t = threadIdx.x;
  const int n0 = blockIdx.x * 64;
  const int b = n0 >> 10, hw0 = n0 & 1023;

  if (t == 0) nflag = 0;
  __syncthreads();
  if (t < 64) {
    kk[t] = (unsigned)(gbest[n0 + t] & 0xFFFFFFFFull);
    if (flags[n0 + t]) { int p = atomicAdd(&nflag, 1); flist[p] = t; }
  }
  __syncthreads();
  const int nf = nflag;

  // exact numpy-replicating recheck (identical op order to R5/R6 verified path)
  for (int fi = 0; fi < nf; ++fi) {
    int r = flist[fi];
    xrow[t] = in[b * BSTRIDE + t * HWDIM + hw0 + r];
    if (t == 0) bmin = ~0ull;
    __syncthreads();
    if (t == 0) rsh = __fadd_rn(pair128_sq(xrow, 1), pair128_sq(xrow + 128, 1));
    __syncthreads();
    float m[4] = {0.f, 0.f, 0.f, 0.f};
    for (int d = 0; d < 256; ++d) {
      float xv = xrow[d];
      const float* wd = wT + (size_t)d * KCODES + t;
      m[0] = fmaf(xv, wd[0], m[0]);
      m[1] = fmaf(xv, wd[256], m[1]);
      m[2] = fmaf(xv, wd[512], m[2]);
      m[3] = fmaf(xv, wd[768], m[3]);
    }
    ull lb = ~0ull;
#pragma unroll
    for (int j = 0; j < 4; ++j) {
      int k = t + j * 256;
      float dist = fmaf(-2.f, m[j], __fadd_rn(rsh, ss[k]));
      ull key = pk(dist, k);
      if (key < lb) lb = key;
    }
    atomicMin(&bmin, lb);
    __syncthreads();
    if (t == 0) {
      kk[r] = (unsigned)(bmin & 0xFFFFFFFFull);
      gbest[n0 + r] = bmin;     // k_enc reads corrected winners
    }
    __syncthreads();
  }

  if (t < 64) atomicAdd(&hist[kk[t]], 1);

  // quantized_st + loss
  const float* inb = in + b * BSTRIDE + hw0;
  float* outb = outq + b * BSTRIDE + hw0;
  const int hwl = t & 63, dl = t >> 6;
  double lsum = 0.0;
  for (int dc = 0; dc < DDIM; dc += 64) {
    __syncthreads();
#pragma unroll
    for (int m = 0; m < 16; ++m) {
      int u = t + m * 256;
      int r = u >> 6, dd = u & 63;
      wrow[r][dd] = w[kk[r] * DDIM + dc + dd];
    }
    __syncthreads();
#pragma unroll
    for (int dd = 0; dd < 64; dd += 4) {
      int d = dc + dd + dl;
      float x = inb[d * HWDIM + hwl];
      float wv = wrow[hwl][dd + dl];
      float diff = __fsub_rn(wv, x);               // fl(quantized - x)
      __builtin_nontemporal_store(__fadd_rn(x, diff), &outb[d * HWDIM + hwl]);
      lsum += (double)diff * (double)diff;
    }
  }
  red[t] = lsum;
  __syncthreads();
  for (int s = 128; s > 0; s >>= 1) {
    if (t < s) red[t] += red[t + s];
    __syncthreads();
  }
  if (t == 0) atomicAdd(loss, red[0]);
}

// one-hot streaming (8 rows/block, grid 4096) + loss/perplexity fold in block 0
__global__ __launch_bounds__(256) void k_enc(
    const ull* __restrict__ gbest, const int* __restrict__ hist,
    const double* __restrict__ loss, f32x2* __restrict__ enc,
    float* __restrict__ out) {
  __shared__ unsigned kk[8];
  __shared__ double red[256];
  const int t = threadIdx.x;
  const int r0 = blockIdx.x * 8;
  if (t < 8) kk[t] = (unsigned)(gbest[r0 + t] & 0xFFFFFFFFull);
  __syncthreads();
  const int r = t >> 5, l = t & 31;
  const int k = (int)kk[r];
  f32x2* dst = enc + (size_t)(r0 + r) * 512;
#pragma unroll
  for (int j = 0; j < 16; ++j) {
    int c2 = l + j * 32;
    f32x2 v;
    v.x = (c2 * 2 == k) ? 1.0f : 0.0f;
    v.y = (c2 * 2 + 1 == k) ? 1.0f : 0.0f;
    __builtin_nontemporal_store(v, &dst[c2]);
  }
  if (blockIdx.x == 0) {   // hist/loss complete after k_quant
    double s = 0.0;
    for (int i = t; i < KCODES; i += 256) {
      double p = (double)hist[i] * (1.0 / 32768.0);
      s += p * log(p + 1e-10);
    }
    red[t] = s;
    __syncthreads();
    for (int st = 128; st > 0; st >>= 1) {
      if (t < st) red[t] += red[t + st];
      __syncthreads();
    }
    if (t == 0) {
      out[8388609] = (float)exp(-red[0]);
      double m = *loss / 8388608.0;
      out[0] = (float)(1.25 * m);   // q_latent + 0.25 * e_latent, identical values
    }
  }
}

extern "C" void kernel_launch(void* const* d_in, const int* in_sizes, int n_in,
                              void* d_out, int out_size, void* d_ws, size_t ws_size,
                              hipStream_t stream) {
  const float* in = (const float*)d_in[0];   // [32,256,32,32]
  const float* w  = (const float*)d_in[1];   // [1024,256]
  float* out = (float*)d_out;

  char* wsb = (char*)d_ws;
  float* wT    = (float*)(wsb + 0);
  float* ssp   = (float*)(wsb + 1048576);
  ull*   gbest = (ull*)  (wsb + 1052672);
  int*   hist  = (int*)  (wsb + 1314816);
  int*   flags = (int*)  (wsb + 1318912);
  double* loss = (double*)(wsb + 1449984);

  // w split scratch in (not-yet-written) encodings region of d_out
  char* ob = (char*)d_out + 33554448;
  unsigned short* wh8 = (unsigned short*)(ob + 0);
  unsigned short* wl8 = (unsigned short*)(ob + 524288);

  k_prep<<<dim3(128), dim3(256), 0, stream>>>(w, wT, ssp, hist, loss, wh8, wl8);
  k_argmfma<<<dim3(512), dim3(256), 0, stream>>>(in, wh8, wl8, ssp, gbest, flags);
  k_quant<<<dim3(512), dim3(256), 0, stream>>>(in, w, wT, ssp, gbest, flags,
                                               hist, out + 1, loss);
  k_enc<<<dim3(4096), dim3(256), 0, stream>>>(gbest, hist, loss,
                                              (f32x2*)(out + 8388610), out);
}

// Round 9
// 485.850 us; speedup vs baseline: 1.1321x; 1.1321x over previous
//
#include <hip/hip_runtime.h>
#include <hip/hip_bf16.h>

#define HWDIM 1024             // 32*32
#define DDIM 256
#define KCODES 1024
#define NROWS 32768            // 32 * 1024
#define BSTRIDE (DDIM * HWDIM) // per-batch stride = 262144
#define GUARD 1.5e-4f          // certified gap (covers 2x dist roundings @256 + split err)

typedef __attribute__((ext_vector_type(8))) short short8;
typedef __attribute__((ext_vector_type(4))) float f32x4;
typedef __attribute__((ext_vector_type(2))) float f32x2;
typedef unsigned long long ull;

// ---- ws byte layout ----
// wT    @0        (1048576)  fp32 codebook transposed [256][1024] (fallback)
// ss    @1048576  (4096)     ||e_k||^2 numpy-pairwise
// gbest @1052672  (262144)   packed (ordered_dist<<32|k) per row
// hist  @1314816  (4096)
// flags @1318912  (131072)   int per row: 1 = needs exact fallback
// loss  @1449984  (8)        double
// ---- scratch in d_out encodings region (overwritten later by k_enc) ----
// ob = (char*)d_out + 33554448: wh8 @0 (524288), wl8 @524288 (524288)

__device__ __forceinline__ unsigned short f2bf(float v) {
  __hip_bfloat16 b = __float2bfloat16(v);
  return *reinterpret_cast<unsigned short*>(&b);
}
__device__ __forceinline__ float bf2f(unsigned short u) {
  __hip_bfloat16 b;
  *reinterpret_cast<unsigned short*>(&b) = u;
  return __bfloat162float(b);
}
__device__ __forceinline__ ull pk(float d, int k) {
  unsigned ub = __float_as_uint(d);
  ub = (ub & 0x80000000u) ? ~ub : (ub | 0x80000000u);  // monotone total order
  return ((ull)ub << 32) | (unsigned)k;
}
__device__ __forceinline__ float keyq(ull key) {
  unsigned ub = (unsigned)(key >> 32);
  unsigned orig = (ub & 0x80000000u) ? (ub & 0x7FFFFFFFu) : ~ub;
  return __uint_as_float(orig);
}

// numpy-exact pairwise sum of squares over 128 elements
__device__ __forceinline__ float pair128_sq(const float* p, int stride) {
  float a[8];
#pragma unroll
  for (int j = 0; j < 8; ++j) { float v = p[j * stride]; a[j] = __fmul_rn(v, v); }
  for (int i = 8; i < 128; i += 8) {
#pragma unroll
    for (int j = 0; j < 8; ++j) {
      float v = p[(i + j) * stride];
      a[j] = __fadd_rn(a[j], __fmul_rn(v, v));
    }
  }
  float s01 = __fadd_rn(a[0], a[1]), s23 = __fadd_rn(a[2], a[3]);
  float s45 = __fadd_rn(a[4], a[5]), s67 = __fadd_rn(a[6], a[7]);
  return __fadd_rn(__fadd_rn(s01, s23), __fadd_rn(s45, s67));
}

// prep: w bf16 hi/lo split [oct][k][8], wT transpose, ss, inits. grid 128.
__global__ __launch_bounds__(256) void k_prep(
    const float* __restrict__ w, float* __restrict__ wT, float* __restrict__ ss,
    int* __restrict__ hist, double* __restrict__ loss,
    unsigned short* __restrict__ wh8, unsigned short* __restrict__ wl8) {
  __shared__ float tile[64][65];
  const int t = threadIdx.x;
  int g = blockIdx.x * 256 + t;   // 32768 = 1024 k x 32 octets
  {
    int k = g >> 5, oct = g & 31;
    const float* p = w + k * DDIM + oct * 8;
    short8 hv, lv;
#pragma unroll
    for (int j = 0; j < 8; ++j) {
      float v = p[j];
      unsigned short h = f2bf(v);
      unsigned short l = f2bf(__fsub_rn(v, bf2f(h)));
      hv[j] = (short)h; lv[j] = (short)l;
    }
    *(short8*)&wh8[oct * 8192 + k * 8] = hv;
    *(short8*)&wl8[oct * 8192 + k * 8] = lv;
  }
  if (g < KCODES) {
    hist[g] = 0;
    const float* p = w + g * DDIM;
    ss[g] = __fadd_rn(pair128_sq(p, 1), pair128_sq(p + 128, 1));
  }
  if (g == 0) *loss = 0.0;
  // transpose (blocks 0..63): w[k][d] -> wT[d][k], 64x64 tiles
  if (blockIdx.x < 64) {
    const int k0 = (blockIdx.x & 15) * 64, d0 = (blockIdx.x >> 4) * 64;
    const int c = t & 63, r = t >> 6;
#pragma unroll
    for (int m = 0; m < 16; ++m)
      tile[r + m * 4][c] = w[(k0 + r + m * 4) * DDIM + d0 + c];
    __syncthreads();
#pragma unroll
    for (int m = 0; m < 16; ++m)
      wT[(size_t)(d0 + r + m * 4) * KCODES + k0 + c] = tile[c][r + m * 4];
  }
}

// single-pass MFMA argmin: block = 64 rows x ALL 1024 codes. grid 512.
// Each wave covers all 64 rows x a disjoint 32-code column per 128-code kb
// -> B read exactly once per block. kb start-phase staggered per block so
// concurrent same-XCD blocks stream DIFFERENT code chunks -> cross-block L2
// reuse of the 1 MB codebook-split (R8: FETCH 414 MB, no reuse).
__global__ __launch_bounds__(256, 2) void k_argmfma(
    const float* __restrict__ in,
    const unsigned short* __restrict__ wh8, const unsigned short* __restrict__ wl8,
    const float* __restrict__ ss, ull* __restrict__ gbest, int* __restrict__ flags) {
  __shared__ __align__(16) unsigned short Ah[32 * 64 * 8];  // 32 KB
  __shared__ __align__(16) unsigned short Al[32 * 64 * 8];  // 32 KB
  __shared__ ull best1[64], best2[64];

  const int t = threadIdx.x;
  const int n0 = blockIdx.x * 64;       // 64 | 1024 -> single batch per block
  const int b = n0 >> 10, hw0 = n0 & 1023;

  // ---- in-kernel split of x rows into LDS (bit-identical formulas to R6) ----
  {
    const int hw = t & 63, dg = t >> 6;
    const float* xp = in + b * BSTRIDE + hw0 + hw;
#pragma unroll
    for (int dd = 0; dd < 64; dd += 2) {
      int d = dg * 64 + dd;
      float f0 = xp[d * HWDIM], f1 = xp[(d + 1) * HWDIM];
      unsigned short h0 = f2bf(f0);
      unsigned short l0 = f2bf(__fsub_rn(f0, bf2f(h0)));
      unsigned short h1 = f2bf(f1);
      unsigned short l1 = f2bf(__fsub_rn(f1, bf2f(h1)));
      int base = ((d >> 3) * 64 + hw) * 8 + (d & 7);   // d even -> u32 pack ok
      *(unsigned*)&Ah[base] = (unsigned)h0 | ((unsigned)h1 << 16);
      *(unsigned*)&Al[base] = (unsigned)l0 | ((unsigned)l1 << 16);
    }
  }
  if (t < 64) { best1[t] = ~0ull; best2[t] = ~0ull; }
  __syncthreads();

  const int wv = t >> 6, ln = t & 63;
  const int cw = wv * 32;               // wave's 32-code column within each kb
  const int l15 = ln & 15, quad = ln >> 4;
  const int kbp = (blockIdx.x >> 3) & 7;  // per-block kb phase stagger

  ull rb1[16], rb2[16];                 // running best/2nd per (rt,reg) row
#pragma unroll
  for (int i = 0; i < 16; ++i) { rb1[i] = ~0ull; rb2[i] = ~0ull; }

  for (int kbi = 0; kbi < 8; ++kbi) {
    const int kb = (kbp + kbi) & 7;     // order-independent: pure min over keys
    const int cb = kb * 128 + cw;
    f32x4 acc[4][2];
#pragma unroll
    for (int rt = 0; rt < 4; ++rt)
#pragma unroll
      for (int ct = 0; ct < 2; ++ct) acc[rt][ct] = (f32x4){0.f, 0.f, 0.f, 0.f};

#pragma unroll
    for (int ki = 0; ki < 8; ++ki) {
      const int obase = ki * 4 + quad;
      short8 ah[4], al[4], bh[2], bl[2];
#pragma unroll
      for (int ct = 0; ct < 2; ++ct) {
        int off = obase * 8192 + (cb + ct * 16 + l15) * 8;
        bh[ct] = *(const short8*)&wh8[off];
        bl[ct] = *(const short8*)&wl8[off];
      }
#pragma unroll
      for (int rt = 0; rt < 4; ++rt) {
        int row = rt * 16 + l15;
        ah[rt] = *(const short8*)&Ah[(obase * 64 + row) * 8];
        al[rt] = *(const short8*)&Al[(obase * 64 + row) * 8];
      }
#pragma unroll
      for (int rt = 0; rt < 4; ++rt)
#pragma unroll
        for (int ct = 0; ct < 2; ++ct) {
          acc[rt][ct] = __builtin_amdgcn_mfma_f32_16x16x32_bf16(ah[rt], bh[ct], acc[rt][ct], 0, 0, 0);
          acc[rt][ct] = __builtin_amdgcn_mfma_f32_16x16x32_bf16(ah[rt], bl[ct], acc[rt][ct], 0, 0, 0);
          acc[rt][ct] = __builtin_amdgcn_mfma_f32_16x16x32_bf16(al[rt], bh[ct], acc[rt][ct], 0, 0, 0);
        }
    }

    // fold this kb's 32 codes into running per-row top-2 (lane-local)
    float sv[2];
#pragma unroll
    for (int ct = 0; ct < 2; ++ct) sv[ct] = ss[cb + ct * 16 + l15];
#pragma unroll
    for (int rt = 0; rt < 4; ++rt)
#pragma unroll
      for (int reg = 0; reg < 4; ++reg) {
        int idx = rt * 4 + reg;
        ull b1 = rb1[idx], b2 = rb2[idx];
#pragma unroll
        for (int ct = 0; ct < 2; ++ct) {
          float q = fmaf(-2.f, acc[rt][ct][reg], sv[ct]);
          ull key = pk(q, cb + ct * 16 + l15);
          if (key < b1) { b2 = b1; b1 = key; } else if (key < b2) { b2 = key; }
        }
        rb1[idx] = b1; rb2[idx] = b2;
      }
  }

  // two-pass block merge: global best, then global 2nd
#pragma unroll
  for (int rt = 0; rt < 4; ++rt)
#pragma unroll
    for (int reg = 0; reg < 4; ++reg)
      atomicMin(&best1[rt * 16 + quad * 4 + reg], rb1[rt * 4 + reg]);
  __syncthreads();
#pragma unroll
  for (int rt = 0; rt < 4; ++rt)
#pragma unroll
    for (int reg = 0; reg < 4; ++reg) {
      int row = rt * 16 + quad * 4 + reg;
      int idx = rt * 4 + reg;
      ull sub = (rb1[idx] == best1[row]) ? rb2[idx] : rb1[idx];
      atomicMin(&best2[row], sub);
    }
  __syncthreads();
  if (t < 64) {
    ull k1 = best1[t];
    gbest[n0 + t] = k1;
    flags[n0 + t] = (keyq(best2[t]) - keyq(k1) > GUARD) ? 0 : 1;
  }
}

// exact fallback for flagged rows + hist + quantized_st/loss. grid 512.
__global__ __launch_bounds__(256) void k_quant(
    const float* __restrict__ in, const float* __restrict__ w,
    const float* __restrict__ wT, const float* __restrict__ ss,
    ull* __restrict__ gbest, const int* __restrict__ flags,
    int* __restrict__ hist, float* __restrict__ outq, double* __restrict__ loss) {
  __shared__ unsigned kk[64];
  __shared__ int flist[64];
  __shared__ int nflag;
  __shared__ float xrow[256];
  __shared__ float rsh;
  __shared__ ull bmin;
  __shared__ float wrow[64][65];
  __shared__ double red[256];

  const int t = threadIdx.x;
  const int n0 = blockIdx.x * 64;
  const int b = n0 >> 10, hw0 = n0 & 1023;

  if (t == 0) nflag = 0;
  __syncthreads();
  if (t < 64) {
    kk[t] = (unsigned)(gbest[n0 + t] & 0xFFFFFFFFull);
    if (flags[n0 + t]) { int p = atomicAdd(&nflag, 1); flist[p] = t; }
  }
  __syncthreads();
  const int nf = nflag;

  // exact numpy-replicating recheck (identical op order to R5/R6 verified path)
  for (int fi = 0; fi < nf; ++fi) {
    int r = flist[fi];
    xrow[t] = in[b * BSTRIDE + t * HWDIM + hw0 + r];
    if (t == 0) bmin = ~0ull;
    __syncthreads();
    if (t == 0) rsh = __fadd_rn(pair128_sq(xrow, 1), pair128_sq(xrow + 128, 1));
    __syncthreads();
    float m[4] = {0.f, 0.f, 0.f, 0.f};
    for (int d = 0; d < 256; ++d) {
      float xv = xrow[d];
      const float* wd = wT + (size_t)d * KCODES + t;
      m[0] = fmaf(xv, wd[0], m[0]);
      m[1] = fmaf(xv, wd[256], m[1]);
      m[2] = fmaf(xv, wd[512], m[2]);
      m[3] = fmaf(xv, wd[768], m[3]);
    }
    ull lb = ~0ull;
#pragma unroll
    for (int j = 0; j < 4; ++j) {
      int k = t + j * 256;
      float dist = fmaf(-2.f, m[j], __fadd_rn(rsh, ss[k]));
      ull key = pk(dist, k);
      if (key < lb) lb = key;
    }
    atomicMin(&bmin, lb);
    __syncthreads();
    if (t == 0) {
      kk[r] = (unsigned)(bmin & 0xFFFFFFFFull);
      gbest[n0 + r] = bmin;     // k_enc reads corrected winners
    }
    __syncthreads();
  }

  if (t < 64) atomicAdd(&hist[kk[t]], 1);

  // quantized_st + loss
  const float* inb = in + b * BSTRIDE + hw0;
  float* outb = outq + b * BSTRIDE + hw0;
  const int hwl = t & 63, dl = t >> 6;
  double lsum = 0.0;
  for (int dc = 0; dc < DDIM; dc += 64) {
    __syncthreads();
#pragma unroll
    for (int m = 0; m < 16; ++m) {
      int u = t + m * 256;
      int r = u >> 6, dd = u & 63;
      wrow[r][dd] = w[kk[r] * DDIM + dc + dd];
    }
    __syncthreads();
#pragma unroll
    for (int dd = 0; dd < 64; dd += 4) {
      int d = dc + dd + dl;
      float x = inb[d * HWDIM + hwl];
      float wv = wrow[hwl][dd + dl];
      float diff = __fsub_rn(wv, x);               // fl(quantized - x)
      outb[d * HWDIM + hwl] = __fadd_rn(x, diff);  // fl(x + fl(q - x)) == np
      lsum += (double)diff * (double)diff;
    }
  }
  red[t] = lsum;
  __syncthreads();
  for (int s = 128; s > 0; s >>= 1) {
    if (t < s) red[t] += red[t + s];
    __syncthreads();
  }
  if (t == 0) atomicAdd(loss, red[0]);
}

// one-hot streaming (8 rows/block, grid 4096) + loss/perplexity fold in block 0
__global__ __launch_bounds__(256) void k_enc(
    const ull* __restrict__ gbest, const int* __restrict__ hist,
    const double* __restrict__ loss, f32x2* __restrict__ enc,
    float* __restrict__ out) {
  __shared__ unsigned kk[8];
  __shared__ double red[256];
  const int t = threadIdx.x;
  const int r0 = blockIdx.x * 8;
  if (t < 8) kk[t] = (unsigned)(gbest[r0 + t] & 0xFFFFFFFFull);
  __syncthreads();
  const int r = t >> 5, l = t & 31;
  const int k = (int)kk[r];
  f32x2* dst = enc + (size_t)(r0 + r) * 512;
#pragma unroll
  for (int j = 0; j < 16; ++j) {
    int c2 = l + j * 32;
    f32x2 v;
    v.x = (c2 * 2 == k) ? 1.0f : 0.0f;
    v.y = (c2 * 2 + 1 == k) ? 1.0f : 0.0f;
    dst[c2] = v;
  }
  if (blockIdx.x == 0) {   // hist/loss complete after k_quant
    double s = 0.0;
    for (int i = t; i < KCODES; i += 256) {
      double p = (double)hist[i] * (1.0 / 32768.0);
      s += p * log(p + 1e-10);
    }
    red[t] = s;
    __syncthreads();
    for (int st = 128; st > 0; st >>= 1) {
      if (t < st) red[t] += red[t + st];
      __syncthreads();
    }
    if (t == 0) {
      out[8388609] = (float)exp(-red[0]);
      double m = *loss / 8388608.0;
      out[0] = (float)(1.25 * m);   // q_latent + 0.25 * e_latent, identical values
    }
  }
}

extern "C" void kernel_launch(void* const* d_in, const int* in_sizes, int n_in,
                              void* d_out, int out_size, void* d_ws, size_t ws_size,
                              hipStream_t stream) {
  const float* in = (const float*)d_in[0];   // [32,256,32,32]
  const float* w  = (const float*)d_in[1];   // [1024,256]
  float* out = (float*)d_out;

  char* wsb = (char*)d_ws;
  float* wT    = (float*)(wsb + 0);
  float* ssp   = (float*)(wsb + 1048576);
  ull*   gbest = (ull*)  (wsb + 1052672);
  int*   hist  = (int*)  (wsb + 1314816);
  int*   flags = (int*)  (wsb + 1318912);
  double* loss = (double*)(wsb + 1449984);

  // w split scratch in (not-yet-written) encodings region of d_out
  char* ob = (char*)d_out + 33554448;
  unsigned short* wh8 = (unsigned short*)(ob + 0);
  unsigned short* wl8 = (unsigned short*)(ob + 524288);

  k_prep<<<dim3(128), dim3(256), 0, stream>>>(w, wT, ssp, hist, loss, wh8, wl8);
  k_argmfma<<<dim3(512), dim3(256), 0, stream>>>(in, wh8, wl8, ssp, gbest, flags);
  k_quant<<<dim3(512), dim3(256), 0, stream>>>(in, w, wT, ssp, gbest, flags,
                                               hist, out + 1, loss);
  k_enc<<<dim3(4096), dim3(256), 0, stream>>>(gbest, hist, loss,
                                              (f32x2*)(out + 8388610), out);
}